// Round 1
// baseline (81.923 us; speedup 1.0000x reference)
//
#include <hip/hip_runtime.h>

// QuantizedLinear: out[t][o] = sum_k x[t][k] * (w_q[o][k]-128)*scale[o] + bias[o]
// M=16, N=8192, K=8192. Memory-bound on w_q (256 MB int32, read once).
//
// Layout: grid 512 blocks x 256 threads (4 waves). Block owns 16 output
// channels (4 per wave). Lanes tile K: lane reads w_q as int4 (4 k's, 16 B)
// from each of its wave's 4 rows -> coalesced 64-lane dwordx4 streams.
// x[16][k-chunk] staged in LDS [t][K_CHUNK]; per k-quad each lane does one
// conflict-free ds_read_b128 per t. (w_q-128) folded into the int->float cvt;
// scale/bias applied after the cross-lane reduction.

#define IN_F   8192
#define OUT_F  8192
#define NT     16          // T (tokens)
#define K_CHUNK 1024
#define BLOCK  256
#define W_O    4           // output channels per wave
#define CH_PER_BLOCK 16    // 4 waves * W_O

__global__ __launch_bounds__(BLOCK, 2)
void qlin_kernel(const float* __restrict__ x,     // [16][8192]
                 const int*   __restrict__ w_q,   // [8192][8192]
                 const float* __restrict__ scale, // [8192]
                 const float* __restrict__ bias,  // [8192]
                 float* __restrict__ out)         // [16][8192]
{
    __shared__ float xs[NT][K_CHUNK];             // 64 KB

    const int tid  = threadIdx.x;
    const int lane = tid & 63;
    const int wave = tid >> 6;
    const int o_base = blockIdx.x * CH_PER_BLOCK + wave * W_O;

    float acc[NT][W_O];
#pragma unroll
    for (int t = 0; t < NT; ++t)
#pragma unroll
        for (int j = 0; j < W_O; ++j) acc[t][j] = 0.0f;

    const int nchunk = IN_F / K_CHUNK;            // 8

    for (int c = 0; c < nchunk; ++c) {
        __syncthreads();                          // xs safe to overwrite
        // ---- stage x chunk: row i, cols [c*K_CHUNK, +K_CHUNK) ----
#pragma unroll
        for (int i = 0; i < NT; ++i) {
            const float4 v = *reinterpret_cast<const float4*>(
                &x[(size_t)i * IN_F + c * K_CHUNK + tid * 4]);
            *reinterpret_cast<float4*>(&xs[i][tid * 4]) = v;
        }
        __syncthreads();

        // ---- compute: wave covers 256 k per iter (64 lanes x int4) ----
#pragma unroll
        for (int it = 0; it < K_CHUNK / 256; ++it) {
            const int kl = it * 256 + lane * 4;   // k within chunk
            const int kg = c * K_CHUNK + kl;      // global k

            float wf[W_O][4];
#pragma unroll
            for (int j = 0; j < W_O; ++j) {
                const int4 w = *reinterpret_cast<const int4*>(
                    &w_q[(size_t)(o_base + j) * IN_F + kg]);
                wf[j][0] = (float)(w.x - 128);
                wf[j][1] = (float)(w.y - 128);
                wf[j][2] = (float)(w.z - 128);
                wf[j][3] = (float)(w.w - 128);
            }
#pragma unroll
            for (int t = 0; t < NT; ++t) {
                const float4 xv = *reinterpret_cast<const float4*>(&xs[t][kl]);
#pragma unroll
                for (int j = 0; j < W_O; ++j) {
                    acc[t][j] += wf[j][0] * xv.x;
                    acc[t][j] += wf[j][1] * xv.y;
                    acc[t][j] += wf[j][2] * xv.z;
                    acc[t][j] += wf[j][3] * xv.w;
                }
            }
        }
    }

    // ---- cross-lane reduction: 64 (t,j) values, 6-step butterfly each ----
    float myval = 0.0f;
#pragma unroll
    for (int t = 0; t < NT; ++t) {
#pragma unroll
        for (int j = 0; j < W_O; ++j) {
            float v = acc[t][j];
#pragma unroll
            for (int off = 32; off > 0; off >>= 1)
                v += __shfl_xor(v, off, 64);
            if (lane == (t * W_O + j)) myval = v;
        }
    }

    // lane l -> (t = l>>2, channel j = l&3)
    const int t_o = lane >> 2;
    const int o   = o_base + (lane & 3);
    out[(size_t)t_o * OUT_F + o] = myval * scale[o] + bias[o];
}

extern "C" void kernel_launch(void* const* d_in, const int* in_sizes, int n_in,
                              void* d_out, int out_size, void* d_ws, size_t ws_size,
                              hipStream_t stream) {
    const float* x     = (const float*)d_in[0];
    const int*   w_q   = (const int*)d_in[1];
    const float* scale = (const float*)d_in[2];
    const float* bias  = (const float*)d_in[3];
    float*       out   = (float*)d_out;

    dim3 grid(OUT_F / CH_PER_BLOCK);   // 512 blocks, 2 per CU
    dim3 block(BLOCK);
    qlin_kernel<<<grid, block, 0, stream>>>(x, w_q, scale, bias, out);
}